// Round 8
// baseline (416.464 us; speedup 1.0000x reference)
//
#include <hip/hip_runtime.h>
#include <stdint.h>

// WASLL R8: deterministic two-sort pipeline (R7 structure) with ragged-tail
// correctness. R7 never ran: NP=8e6 is not a multiple of 16384, guard -> R1
// fallback (156us). Fix: bucket BASES are exact (aligned ranges) even with a
// ragged last bucket; all sizes come from the measured cnt table; bounds
// checks everywhere; count-table columns padded to fixed 1024 (zeros inert).
//   P1a: chunk 16384 = one j-bucket; LDS hist -> cnt[jb][1024]
//   P1b: scan over jb -> ofs1 (ent1 cells); per-row scan over pinb -> ofs2
//   P1c: stream fnp, LDS-atomic rank, write pinoff16/jarr at ofs1+rank
//   P2:  per pin-bucket: 32KB LDS pos window, gather+quantize, LDS-atomic
//        rank, write ent2[ofs2+rank] = (slot14<<18)|yq18
//   P3:  per j-bucket: 64KB LDS slot tile, per-net wa4, reduce, 1 atomic/blk
// No global cursor atomics, no scans/staging in hot passes (R6 lesson).
// ent1 split u16+u32 (6B/entry): ws ~86MB < R6-proven >=96MB.
// Max-shift dropped (cancels in ratio; |arg|<=span*ig~8). Quant err << thr.

#define PB_SHIFT   13
#define PB_SIZE    (1 << PB_SHIFT)        // 8192 pins per pin-bucket
#define NPB_PAD    1024
#define JB_SHIFT   14
#define JB_SIZE    (1 << JB_SHIFT)        // 16384 slots per j-bucket
#define MAX_NJB    512
#define CH         JB_SIZE
#define YQ_SHIFT   18
#define YQ_ONE     262144.0f
#define YQ_MASK    ((1u << YQ_SHIFT) - 1u)

__device__ __forceinline__ float wa4(float a, float b, float c, float d, float ig) {
    float ea = __expf(a * ig), eb = __expf(b * ig);
    float ec = __expf(c * ig), ed = __expf(d * ig);
    float na = __expf(-a * ig), nb = __expf(-b * ig);
    float nc = __expf(-c * ig), nd = __expf(-d * ig);
    float s_ep  = ea + eb + ec + ed;
    float s_xep = a * ea + b * eb + c * ec + d * ed;
    float s_en  = na + nb + nc + nd;
    float s_xen = a * na + b * nb + c * nc + d * nd;
    return s_xep / s_ep - s_xen / s_en;
}

// ---- P1a: per 16384-chunk (== j-bucket), count pins per pin-bucket ----
__global__ __launch_bounds__(512) void p1a_count(
    const int4* __restrict__ fnp4, int NP, unsigned* __restrict__ cnt)
{
    __shared__ unsigned hist[NPB_PAD];
    const int c = blockIdx.x, t = threadIdx.x;
    const int base  = c * CH;
    const int valid = min(CH, NP - base);          // multiple of 4
    for (int i = t; i < NPB_PAD; i += 512) hist[i] = 0;
    __syncthreads();
    #pragma unroll
    for (int m = 0; m < 8; ++m) {
        int k4 = t + 512 * m;
        if (4 * k4 < valid) {
            int4 v = fnp4[(base >> 2) + k4];
            atomicAdd(&hist[(unsigned)v.x >> PB_SHIFT], 1u);
            atomicAdd(&hist[(unsigned)v.y >> PB_SHIFT], 1u);
            atomicAdd(&hist[(unsigned)v.z >> PB_SHIFT], 1u);
            atomicAdd(&hist[(unsigned)v.w >> PB_SHIFT], 1u);
        }
    }
    __syncthreads();
    for (int i = t; i < NPB_PAD; i += 512)
        cnt[(size_t)c * NPB_PAD + i] = hist[i];
}

// ---- P1b: ofs1 = scan of cnt over jb (per pinb); ofs2 = per-row scan ----
__global__ __launch_bounds__(256) void p1b_scan(
    const unsigned* __restrict__ cnt, int NJB,
    unsigned* __restrict__ ofs1, unsigned* __restrict__ ofs2,
    float* __restrict__ out)
{
    const int blk = blockIdx.x, t = threadIdx.x;
    if (blk == 0 && t == 0) out[0] = 0.0f;
    if (blk < 4) {                                 // scan1: 1024 pinb columns
        const int p = blk * 256 + t;
        unsigned acc = (unsigned)p << PB_SHIFT;    // exact bucket base
        for (int c0 = 0; c0 < NJB; c0 += 8) {
            unsigned v[8];
            #pragma unroll
            for (int i = 0; i < 8; ++i)
                v[i] = (c0 + i < NJB) ? cnt[(size_t)(c0 + i) * NPB_PAD + p] : 0u;
            #pragma unroll
            for (int i = 0; i < 8; ++i) {
                if (c0 + i < NJB) ofs1[(size_t)(c0 + i) * NPB_PAD + p] = acc;
                acc += v[i];
            }
        }
    } else {                                       // scan2: one block per jb row
        const int jb = blk - 4;
        if (jb >= NJB) return;
        __shared__ unsigned wsum[4];
        const uint4* row = (const uint4*)(cnt + (size_t)jb * NPB_PAD);
        uint4 v = row[t];                          // 4 consecutive pinb counts
        unsigned s = v.x + v.y + v.z + v.w;
        unsigned ex = s;
        #pragma unroll
        for (int off = 1; off < 64; off <<= 1) {
            unsigned u = __shfl_up(ex, off, 64);
            if ((t & 63) >= off) ex += u;
        }
        ex -= s;
        if ((t & 63) == 63) wsum[t >> 6] = ex + s;
        __syncthreads();
        unsigned wb = 0;
        const int w = t >> 6;
        #pragma unroll
        for (int i = 0; i < 4; ++i) if (i < w) wb += wsum[i];
        unsigned o = ((unsigned)jb << JB_SHIFT) + wb + ex;  // exact jb base
        uint4 ov;
        ov.x = o; ov.y = o + v.x; ov.z = ov.y + v.y; ov.w = ov.z + v.z;
        ((uint4*)(ofs2 + (size_t)jb * NPB_PAD))[t] = ov;
    }
}

// ---- P1c: stream fnp, LDS-atomic rank, split scatter (pinoff16 + jarr) ----
__global__ __launch_bounds__(512) void p1c_scatter(
    const int4* __restrict__ fnp4, const unsigned* __restrict__ ofs1,
    int NP, unsigned short* __restrict__ pinoff16, unsigned* __restrict__ jarr)
{
    __shared__ unsigned hist[NPB_PAD];
    __shared__ unsigned orow[NPB_PAD];
    const int c = blockIdx.x, t = threadIdx.x;
    const int base  = c * CH;
    const int valid = min(CH, NP - base);
    for (int i = t; i < NPB_PAD; i += 512) {
        hist[i] = 0;
        orow[i] = ofs1[(size_t)c * NPB_PAD + i];
    }
    __syncthreads();
    int4 v[8];
    #pragma unroll
    for (int m = 0; m < 8; ++m) {                  // batch loads for MLP
        int k4 = t + 512 * m;
        v[m] = (4 * k4 < valid) ? fnp4[(base >> 2) + k4] : make_int4(-1, -1, -1, -1);
    }
    #pragma unroll
    for (int m = 0; m < 8; ++m) {
        int k4 = t + 512 * m;
        if (4 * k4 >= valid) continue;
        unsigned pin[4] = {(unsigned)v[m].x, (unsigned)v[m].y,
                           (unsigned)v[m].z, (unsigned)v[m].w};
        #pragma unroll
        for (int i = 0; i < 4; ++i) {
            unsigned pb  = pin[i] >> PB_SHIFT;
            unsigned r   = atomicAdd(&hist[pb], 1u);
            unsigned dst = orow[pb] + r;
            pinoff16[dst] = (unsigned short)(pin[i] & (PB_SIZE - 1u));
            jarr[dst]     = (unsigned)(base + 4 * k4 + i);
        }
    }
}

// ---- P2: per pin-bucket LDS window gather + quantize + scatter to ent2 ----
// LDS: 32KB win + 2KB hist + 2KB orow = 36KB -> 4 blocks/CU. 1 barrier.
__global__ __launch_bounds__(512) void p2_gather(
    const unsigned short* __restrict__ pinoff16, const unsigned* __restrict__ jarr,
    const float2* __restrict__ pos2, const unsigned* __restrict__ ofs2,
    const int* __restrict__ slrx_p, const int* __restrict__ slry_p,
    int d, int NP, int NJB, unsigned* __restrict__ ent2)
{
    const int slr = (d == 0) ? slrx_p[0] : slry_p[0];
    if (slr <= 1) return;
    const float qs = YQ_ONE / (float)slr;

    __shared__ float    win[PB_SIZE];
    __shared__ unsigned hist[MAX_NJB];
    __shared__ unsigned orow[MAX_NJB];
    const int p = blockIdx.x, t = threadIdx.x;
    const int pbase   = p << PB_SHIFT;
    const int count_b = min(PB_SIZE, NP - pbase);

    for (int i = t; i < count_b; i += 512) {       // coalesced window load
        float2 q = pos2[pbase + i];
        win[i] = d ? q.y : q.x;
    }
    for (int i = t; i < NJB; i += 512) {
        hist[i] = 0;
        orow[i] = ofs2[(size_t)i * NPB_PAD + p];   // L2-hot (2MB table)
    }
    __syncthreads();

    unsigned short po[16]; unsigned jv[16];
    #pragma unroll
    for (int m = 0; m < 16; ++m) {                 // batch coalesced loads
        int k = t + 512 * m;
        po[m] = (k < count_b) ? pinoff16[pbase + k] : 0;
        jv[m] = (k < count_b) ? jarr[pbase + k] : 0u;
    }
    #pragma unroll
    for (int m = 0; m < 16; ++m) {
        int k = t + 512 * m;
        if (k >= count_b) continue;
        float y = win[po[m]];                      // LDS gather
        unsigned yq = min((unsigned)(y * qs + 0.5f), YQ_MASK);
        unsigned jb = jv[m] >> JB_SHIFT;
        unsigned r  = atomicAdd(&hist[jb], 1u);    // local rank only
        ent2[orow[jb] + r] = ((jv[m] & (JB_SIZE - 1u)) << YQ_SHIFT) | yq;
    }
}

// ---- P3: per j-bucket LDS slot tile, per-net wa4, reduce ----
__global__ __launch_bounds__(512) void p3_compute(
    const unsigned* __restrict__ ent2, const float* __restrict__ wts,
    const float* __restrict__ ig_p,
    const int* __restrict__ slrx_p, const int* __restrict__ slry_p,
    int d, int NP, float* __restrict__ out)
{
    const int slr = (d == 0) ? slrx_p[0] : slry_p[0];
    if (slr <= 1) return;
    const float dq = (float)slr / YQ_ONE;

    __shared__ float ytmp[JB_SIZE];                // 64KB
    const int bj = blockIdx.x << JB_SHIFT, t = threadIdx.x;
    const int nslots = min(JB_SIZE, NP - bj);      // multiple of 4
    const float ig = ig_p[0];

    for (int k = t; k < nslots; k += 512) {        // coalesced read, slot scatter
        unsigned e = ent2[bj + k];
        ytmp[e >> YQ_SHIFT] = (float)(e & YQ_MASK) * dq;
    }
    __syncthreads();

    float val = 0.0f;
    const int nnets = nslots >> 2, bnet = bj >> 2;
    const float4* y4 = (const float4*)ytmp;
    for (int i = t; i < nnets; i += 512) {
        float4 q = y4[i];                          // ds_read_b128
        val += wts[bnet + i] * wa4(q.x, q.y, q.z, q.w, ig);
    }

    #pragma unroll
    for (int off = 32; off > 0; off >>= 1) val += __shfl_down(val, off, 64);
    __syncthreads();
    if ((t & 63) == 0) ytmp[t >> 6] = val;
    __syncthreads();
    if (t == 0) {
        float s = 0.0f;
        #pragma unroll
        for (int w = 0; w < 8; ++w) s += ytmp[w];
        atomicAdd(out, s);
    }
}

// ---------------- fallback: proven R1 gather kernel ----------------
__global__ __launch_bounds__(256) void wasll_fallback(
    const float2* __restrict__ pos, const int4* __restrict__ fnp4,
    const float* __restrict__ net_weights, const float* __restrict__ inv_gamma_p,
    const int* __restrict__ slrx_p, const int* __restrict__ slry_p,
    float* __restrict__ out, int num_nets)
{
    const float ig = inv_gamma_p[0];
    const float dx = (slrx_p[0] > 1) ? 1.0f : 0.0f;
    const float dy = (slry_p[0] > 1) ? 1.0f : 0.0f;
    int net = blockIdx.x * blockDim.x + threadIdx.x;
    float val = 0.0f;
    if (net < num_nets) {
        int4 idx = fnp4[net];
        float2 p0 = pos[idx.x], p1 = pos[idx.y], p2 = pos[idx.z], p3 = pos[idx.w];
        val = net_weights[net] * (dx * wa4(p0.x, p1.x, p2.x, p3.x, ig)
                                + dy * wa4(p0.y, p1.y, p2.y, p3.y, ig));
    }
    #pragma unroll
    for (int off = 32; off > 0; off >>= 1) val += __shfl_down(val, off, 64);
    __shared__ float smem[4];
    if ((threadIdx.x & 63) == 0) smem[threadIdx.x >> 6] = val;
    __syncthreads();
    if (threadIdx.x == 0)
        atomicAdd(out, smem[0] + smem[1] + smem[2] + smem[3]);
}

__global__ void zero_out_kernel(float* __restrict__ out) { out[0] = 0.0f; }

extern "C" void kernel_launch(void* const* d_in, const int* in_sizes, int n_in,
                              void* d_out, int out_size, void* d_ws, size_t ws_size,
                              hipStream_t stream) {
    const float* posf        = (const float*)d_in[0];
    const int*   fnp         = (const int*)d_in[1];
    const float* net_weights = (const float*)d_in[4];
    const float* inv_gamma   = (const float*)d_in[7];
    const int*   slrx        = (const int*)d_in[8];
    const int*   slry        = (const int*)d_in[9];
    float*       out         = (float*)d_out;
    const int    N  = in_sizes[4];
    const int    NP = in_sizes[1];

    const int NJB = (NP + CH - 1) / CH;            // j-buckets == P1 chunks
    const int NPB = (NP + PB_SIZE - 1) / PB_SIZE;  // real pin-buckets

    size_t off = 0;
    auto carve = [&](size_t bytes) { size_t o = off; off += (bytes + 255) & ~size_t(255); return o; };
    size_t o_po   = carve((size_t)NP * sizeof(unsigned short));
    size_t o_jarr = carve((size_t)NP * sizeof(unsigned));
    size_t o_ent2 = carve((size_t)NP * sizeof(unsigned));
    size_t o_cnt  = carve((size_t)NJB * NPB_PAD * sizeof(unsigned));
    size_t o_ofs1 = carve((size_t)NJB * NPB_PAD * sizeof(unsigned));
    size_t o_ofs2 = carve((size_t)NJB * NPB_PAD * sizeof(unsigned));

    const bool ok = (NP == 4 * N) && (NP % 4 == 0) &&
                    (NPB <= NPB_PAD) && (NJB <= MAX_NJB) && (off <= ws_size);
    if (!ok) {
        hipLaunchKernelGGL(zero_out_kernel, dim3(1), dim3(1), 0, stream, out);
        const int block = 256, grid = (N + block - 1) / block;
        hipLaunchKernelGGL(wasll_fallback, dim3(grid), dim3(block), 0, stream,
                           (const float2*)posf, (const int4*)fnp, net_weights,
                           inv_gamma, slrx, slry, out, N);
        return;
    }

    char* ws = (char*)d_ws;
    unsigned short* pinoff16 = (unsigned short*)(ws + o_po);
    unsigned*       jarr     = (unsigned*)(ws + o_jarr);
    unsigned*       ent2     = (unsigned*)(ws + o_ent2);
    unsigned*       cnt      = (unsigned*)(ws + o_cnt);
    unsigned*       ofs1     = (unsigned*)(ws + o_ofs1);
    unsigned*       ofs2     = (unsigned*)(ws + o_ofs2);

    hipLaunchKernelGGL(p1a_count, dim3(NJB), dim3(512), 0, stream,
                       (const int4*)fnp, NP, cnt);
    hipLaunchKernelGGL(p1b_scan, dim3(4 + NJB), dim3(256), 0, stream,
                       cnt, NJB, ofs1, ofs2, out);
    hipLaunchKernelGGL(p1c_scatter, dim3(NJB), dim3(512), 0, stream,
                       (const int4*)fnp, ofs1, NP, pinoff16, jarr);

    // d = 0 (x): early-exits when num_slrX <= 1
    hipLaunchKernelGGL(p2_gather, dim3(NPB), dim3(512), 0, stream,
                       pinoff16, jarr, (const float2*)posf, ofs2,
                       slrx, slry, 0, NP, NJB, ent2);
    hipLaunchKernelGGL(p3_compute, dim3(NJB), dim3(512), 0, stream,
                       ent2, net_weights, inv_gamma, slrx, slry, 0, NP, out);
    // d = 1 (y)
    hipLaunchKernelGGL(p2_gather, dim3(NPB), dim3(512), 0, stream,
                       pinoff16, jarr, (const float2*)posf, ofs2,
                       slrx, slry, 1, NP, NJB, ent2);
    hipLaunchKernelGGL(p3_compute, dim3(NJB), dim3(512), 0, stream,
                       ent2, net_weights, inv_gamma, slrx, slry, 1, NP, out);
}

// Round 9
// 326.165 us; speedup vs baseline: 1.2769x; 1.2769x over previous
//
#include <hip/hip_runtime.h>
#include <stdint.h>

// WASLL R9: deterministic two-sort with LDS-staged scatter writes.
// R8 evidence: p1c direct rank-scatter = 400MB HBM writes (8x amplification,
// partial 64B lines split across XCD L2s), 163us @ 1.3% VALU. Fix:
//   - p1c stages the chunk's permutation in LDS, then writes bucket runs
//     coalesced (one pass, deterministic offsets, zero global atomics)
//   - XCD-contiguous swizzle (c = (blk&7)*Q + blk>>3) on p1c and p2 so
//     adjacent chunks/buckets share one L2 and boundary lines merge
//   - tables at 8192-entry chunk granularity; ofs2 rows sum chunk pairs
// Pipeline: p1a count -> p1b scans (ofs1, ofs2) -> p1c scatter (pinoff16 +
// jarr) -> p2 window-gather + quantize -> ent2 (slot14<<18|yq18) -> p3 LDS
// slot tile + wa4 + reduce. Max-shift dropped (cancels in ratio, |arg|<=8).

#define PB_SHIFT   13
#define PB_SIZE    (1 << PB_SHIFT)        // 8192 pins per pin-bucket
#define NPB_PAD    1024
#define JB_SHIFT   14
#define JB_SIZE    (1 << JB_SHIFT)        // 16384 slots per j-bucket
#define MAX_NJB    512
#define CH1        8192                   // p1 chunk (== staging capacity)
#define YQ_SHIFT   18
#define YQ_ONE     262144.0f
#define YQ_MASK    ((1u << YQ_SHIFT) - 1u)

__device__ __forceinline__ float wa4(float a, float b, float c, float d, float ig) {
    float ea = __expf(a * ig), eb = __expf(b * ig);
    float ec = __expf(c * ig), ed = __expf(d * ig);
    float na = __expf(-a * ig), nb = __expf(-b * ig);
    float nc = __expf(-c * ig), nd = __expf(-d * ig);
    float s_ep  = ea + eb + ec + ed;
    float s_xep = a * ea + b * eb + c * ec + d * ed;
    float s_en  = na + nb + nc + nd;
    float s_xen = a * na + b * nb + c * nc + d * nd;
    return s_xep / s_ep - s_xen / s_en;
}

// ---- P1a: per 8192-chunk, count pins per pin-bucket -> cnt[ch][1024] ----
__global__ __launch_bounds__(512) void p1a_count(
    const int4* __restrict__ fnp4, int NP, unsigned* __restrict__ cnt)
{
    __shared__ unsigned hist[NPB_PAD];
    const int c = blockIdx.x, t = threadIdx.x;
    const int base  = c * CH1;
    const int valid = min(CH1, NP - base);         // multiple of 4
    for (int i = t; i < NPB_PAD; i += 512) hist[i] = 0;
    __syncthreads();
    #pragma unroll
    for (int m = 0; m < 4; ++m) {
        int k4 = t + 512 * m;
        if (4 * k4 < valid) {
            int4 v = fnp4[(base >> 2) + k4];
            atomicAdd(&hist[(unsigned)v.x >> PB_SHIFT], 1u);
            atomicAdd(&hist[(unsigned)v.y >> PB_SHIFT], 1u);
            atomicAdd(&hist[(unsigned)v.z >> PB_SHIFT], 1u);
            atomicAdd(&hist[(unsigned)v.w >> PB_SHIFT], 1u);
        }
    }
    __syncthreads();
    for (int i = t; i < NPB_PAD; i += 512)
        cnt[(size_t)c * NPB_PAD + i] = hist[i];
}

// ---- P1b: ofs1[ch][pb] (scan over ch); ofs2[jb][pb] (row scan, ch pairs) ----
__global__ __launch_bounds__(256) void p1b_scan(
    const unsigned* __restrict__ cnt, int NCH, int NJB,
    unsigned* __restrict__ ofs1, unsigned* __restrict__ ofs2,
    float* __restrict__ out)
{
    const int blk = blockIdx.x, t = threadIdx.x;
    if (blk == 0 && t == 0) out[0] = 0.0f;
    if (blk < 4) {                                 // scan1: 1024 pinb columns
        const int p = blk * 256 + t;
        unsigned acc = (unsigned)p << PB_SHIFT;    // exact bucket base
        for (int c0 = 0; c0 < NCH; c0 += 8) {
            unsigned v[8];
            #pragma unroll
            for (int i = 0; i < 8; ++i)
                v[i] = (c0 + i < NCH) ? cnt[(size_t)(c0 + i) * NPB_PAD + p] : 0u;
            #pragma unroll
            for (int i = 0; i < 8; ++i) {
                if (c0 + i < NCH) ofs1[(size_t)(c0 + i) * NPB_PAD + p] = acc;
                acc += v[i];
            }
        }
    } else {                                       // scan2: one block per jb
        const int jb = blk - 4;
        if (jb >= NJB) return;
        __shared__ unsigned wsum[4];
        const int r0 = 2 * jb, r1 = 2 * jb + 1;
        const uint4* rowA = (const uint4*)(cnt + (size_t)r0 * NPB_PAD);
        const uint4* rowB = (const uint4*)(cnt + (size_t)r1 * NPB_PAD);
        uint4 v = rowA[t];
        if (r1 < NCH) {
            uint4 b = rowB[t];
            v.x += b.x; v.y += b.y; v.z += b.z; v.w += b.w;
        }
        unsigned s = v.x + v.y + v.z + v.w;
        unsigned ex = s;
        #pragma unroll
        for (int off = 1; off < 64; off <<= 1) {
            unsigned u = __shfl_up(ex, off, 64);
            if ((t & 63) >= off) ex += u;
        }
        ex -= s;
        if ((t & 63) == 63) wsum[t >> 6] = ex + s;
        __syncthreads();
        unsigned wb = 0;
        const int w = t >> 6;
        #pragma unroll
        for (int i = 0; i < 4; ++i) if (i < w) wb += wsum[i];
        unsigned o = ((unsigned)jb << JB_SHIFT) + wb + ex;  // exact jb base
        uint4 ov;
        ov.x = o; ov.y = o + v.x; ov.z = ov.y + v.y; ov.w = ov.z + v.z;
        ((uint4*)(ofs2 + (size_t)jb * NPB_PAD))[t] = ov;
    }
}

// ---- P1c: LDS-staged chunk scatter -> coalesced bucket-run writes ----
// LDS: pinS 32K + joffS 16K + hist 4K + scn 4K + orow 4K = 60KB -> 2 blk/CU.
__global__ __launch_bounds__(512) void p1c_scatter(
    const int4* __restrict__ fnp4, const unsigned* __restrict__ ofs1,
    int NP, int NCH, int Q,
    unsigned short* __restrict__ pinoff16, unsigned* __restrict__ jarr)
{
    const int c = (blockIdx.x & 7) * Q + (blockIdx.x >> 3);  // XCD-contiguous
    if (c >= NCH) return;
    __shared__ unsigned       pinS[CH1];
    __shared__ unsigned short joffS[CH1];
    __shared__ unsigned       hist[NPB_PAD];
    __shared__ unsigned       scn[NPB_PAD];
    __shared__ unsigned       orow[NPB_PAD];
    __shared__ unsigned       wsum[8];
    const int t = threadIdx.x;
    const int base  = c * CH1;
    const int valid = min(CH1, NP - base);

    for (int i = t; i < NPB_PAD; i += 512) {
        hist[i] = 0;
        orow[i] = ofs1[(size_t)c * NPB_PAD + i];
    }
    __syncthreads();                               // B1

    unsigned pin[16], rnk[16];
    #pragma unroll
    for (int m4 = 0; m4 < 4; ++m4) {
        int k4 = t + 512 * m4;
        int4 v = make_int4(0, 0, 0, 0);
        if (4 * k4 < valid) v = fnp4[(base >> 2) + k4];
        pin[4*m4+0] = (unsigned)v.x; pin[4*m4+1] = (unsigned)v.y;
        pin[4*m4+2] = (unsigned)v.z; pin[4*m4+3] = (unsigned)v.w;
    }
    #pragma unroll
    for (int m = 0; m < 16; ++m) {
        int kk = 4 * (t + 512 * (m >> 2)) + (m & 3);
        rnk[m] = 0;
        if (kk < valid) rnk[m] = atomicAdd(&hist[pin[m] >> PB_SHIFT], 1u);
    }
    __syncthreads();                               // B2

    // block scan of hist[1024] -> scn (exclusive), 2 buckets/thread
    unsigned h0 = hist[2 * t], h1 = hist[2 * t + 1];
    unsigned s = h0 + h1, ex = s;
    #pragma unroll
    for (int off = 1; off < 64; off <<= 1) {
        unsigned u = __shfl_up(ex, off, 64);
        if ((t & 63) >= off) ex += u;
    }
    ex -= s;
    if ((t & 63) == 63) wsum[t >> 6] = ex + s;
    __syncthreads();                               // B3
    unsigned wb = 0;
    const int w = t >> 6;
    #pragma unroll
    for (int i = 0; i < 8; ++i) if (i < w) wb += wsum[i];
    scn[2 * t]     = wb + ex;
    scn[2 * t + 1] = wb + ex + h0;
    __syncthreads();                               // B4

    #pragma unroll
    for (int m = 0; m < 16; ++m) {                 // stage into bucket order
        int kk = 4 * (t + 512 * (m >> 2)) + (m & 3);
        if (kk < valid) {
            unsigned pos = scn[pin[m] >> PB_SHIFT] + rnk[m];
            pinS[pos]  = pin[m];
            joffS[pos] = (unsigned short)kk;       // kk < 8192
        }
    }
    __syncthreads();                               // B5

    for (int k = t; k < valid; k += 512) {         // coalesced run writes
        unsigned pv = pinS[k];
        unsigned pb = pv >> PB_SHIFT;
        unsigned dst = orow[pb] + ((unsigned)k - scn[pb]);
        pinoff16[dst] = (unsigned short)(pv & (PB_SIZE - 1u));
        jarr[dst]     = (unsigned)base + (unsigned)joffS[k];
    }
}

// ---- P2: per pin-bucket LDS window gather + quantize + scatter to ent2 ----
// LDS: 32KB win + 2KB hist + 2KB orow = 36KB -> 4 blocks/CU.
__global__ __launch_bounds__(512) void p2_gather(
    const unsigned short* __restrict__ pinoff16, const unsigned* __restrict__ jarr,
    const float2* __restrict__ pos2, const unsigned* __restrict__ ofs2,
    const int* __restrict__ slrx_p, const int* __restrict__ slry_p,
    int d, int NP, int NPB, int NJB, int Q, unsigned* __restrict__ ent2)
{
    const int slr = (d == 0) ? slrx_p[0] : slry_p[0];
    if (slr <= 1) return;
    const int p = (blockIdx.x & 7) * Q + (blockIdx.x >> 3);  // XCD-contiguous
    if (p >= NPB) return;
    const float qs = YQ_ONE / (float)slr;

    __shared__ float    win[PB_SIZE];
    __shared__ unsigned hist[MAX_NJB];
    __shared__ unsigned orow[MAX_NJB];
    const int t = threadIdx.x;
    const int pbase   = p << PB_SHIFT;
    const int count_b = min(PB_SIZE, NP - pbase);

    for (int i = t; i < count_b; i += 512) {       // coalesced window load
        float2 q = pos2[pbase + i];
        win[i] = d ? q.y : q.x;
    }
    for (int i = t; i < NJB; i += 512) {
        hist[i] = 0;
        orow[i] = ofs2[(size_t)i * NPB_PAD + p];
    }
    __syncthreads();

    unsigned short po[16]; unsigned jv[16];
    #pragma unroll
    for (int m = 0; m < 16; ++m) {                 // batch coalesced loads
        int k = t + 512 * m;
        po[m] = (k < count_b) ? pinoff16[pbase + k] : 0;
        jv[m] = (k < count_b) ? jarr[pbase + k] : 0u;
    }
    #pragma unroll
    for (int m = 0; m < 16; ++m) {
        int k = t + 512 * m;
        if (k >= count_b) continue;
        float y = win[po[m]];                      // LDS gather
        unsigned yq = min((unsigned)(y * qs + 0.5f), YQ_MASK);
        unsigned jb = jv[m] >> JB_SHIFT;
        unsigned r  = atomicAdd(&hist[jb], 1u);    // local rank only
        ent2[orow[jb] + r] = ((jv[m] & (JB_SIZE - 1u)) << YQ_SHIFT) | yq;
    }
}

// ---- P3: per j-bucket LDS slot tile, per-net wa4, reduce ----
__global__ __launch_bounds__(512) void p3_compute(
    const unsigned* __restrict__ ent2, const float* __restrict__ wts,
    const float* __restrict__ ig_p,
    const int* __restrict__ slrx_p, const int* __restrict__ slry_p,
    int d, int NP, float* __restrict__ out)
{
    const int slr = (d == 0) ? slrx_p[0] : slry_p[0];
    if (slr <= 1) return;
    const float dq = (float)slr / YQ_ONE;

    __shared__ float ytmp[JB_SIZE];                // 64KB
    const int bj = blockIdx.x << JB_SHIFT, t = threadIdx.x;
    const int nslots = min(JB_SIZE, NP - bj);      // multiple of 4
    const float ig = ig_p[0];

    for (int k = t; k < nslots; k += 512) {        // coalesced read, slot scatter
        unsigned e = ent2[bj + k];
        ytmp[e >> YQ_SHIFT] = (float)(e & YQ_MASK) * dq;
    }
    __syncthreads();

    float val = 0.0f;
    const int nnets = nslots >> 2, bnet = bj >> 2;
    const float4* y4 = (const float4*)ytmp;
    for (int i = t; i < nnets; i += 512) {
        float4 q = y4[i];                          // ds_read_b128
        val += wts[bnet + i] * wa4(q.x, q.y, q.z, q.w, ig);
    }

    #pragma unroll
    for (int off = 32; off > 0; off >>= 1) val += __shfl_down(val, off, 64);
    __syncthreads();
    if ((t & 63) == 0) ytmp[t >> 6] = val;
    __syncthreads();
    if (t == 0) {
        float s = 0.0f;
        #pragma unroll
        for (int w = 0; w < 8; ++w) s += ytmp[w];
        atomicAdd(out, s);
    }
}

// ---------------- fallback: proven R1 gather kernel ----------------
__global__ __launch_bounds__(256) void wasll_fallback(
    const float2* __restrict__ pos, const int4* __restrict__ fnp4,
    const float* __restrict__ net_weights, const float* __restrict__ inv_gamma_p,
    const int* __restrict__ slrx_p, const int* __restrict__ slry_p,
    float* __restrict__ out, int num_nets)
{
    const float ig = inv_gamma_p[0];
    const float dx = (slrx_p[0] > 1) ? 1.0f : 0.0f;
    const float dy = (slry_p[0] > 1) ? 1.0f : 0.0f;
    int net = blockIdx.x * blockDim.x + threadIdx.x;
    float val = 0.0f;
    if (net < num_nets) {
        int4 idx = fnp4[net];
        float2 p0 = pos[idx.x], p1 = pos[idx.y], p2 = pos[idx.z], p3 = pos[idx.w];
        val = net_weights[net] * (dx * wa4(p0.x, p1.x, p2.x, p3.x, ig)
                                + dy * wa4(p0.y, p1.y, p2.y, p3.y, ig));
    }
    #pragma unroll
    for (int off = 32; off > 0; off >>= 1) val += __shfl_down(val, off, 64);
    __shared__ float smem[4];
    if ((threadIdx.x & 63) == 0) smem[threadIdx.x >> 6] = val;
    __syncthreads();
    if (threadIdx.x == 0)
        atomicAdd(out, smem[0] + smem[1] + smem[2] + smem[3]);
}

__global__ void zero_out_kernel(float* __restrict__ out) { out[0] = 0.0f; }

extern "C" void kernel_launch(void* const* d_in, const int* in_sizes, int n_in,
                              void* d_out, int out_size, void* d_ws, size_t ws_size,
                              hipStream_t stream) {
    const float* posf        = (const float*)d_in[0];
    const int*   fnp         = (const int*)d_in[1];
    const float* net_weights = (const float*)d_in[4];
    const float* inv_gamma   = (const float*)d_in[7];
    const int*   slrx        = (const int*)d_in[8];
    const int*   slry        = (const int*)d_in[9];
    float*       out         = (float*)d_out;
    const int    N  = in_sizes[4];
    const int    NP = in_sizes[1];

    const int NCH = (NP + CH1 - 1) / CH1;          // p1 chunks
    const int NPB = (NP + PB_SIZE - 1) / PB_SIZE;  // pin-buckets (== NCH here)
    const int NJB = (NP + JB_SIZE - 1) / JB_SIZE;  // j-buckets
    const int Qc  = (NCH + 7) / 8;
    const int Qp  = (NPB + 7) / 8;

    size_t off = 0;
    auto carve = [&](size_t bytes) { size_t o = off; off += (bytes + 255) & ~size_t(255); return o; };
    size_t o_po   = carve((size_t)NP * sizeof(unsigned short));
    size_t o_jarr = carve((size_t)NP * sizeof(unsigned));
    size_t o_ent2 = carve((size_t)NP * sizeof(unsigned));
    size_t o_cnt  = carve((size_t)NCH * NPB_PAD * sizeof(unsigned));
    size_t o_ofs1 = carve((size_t)NCH * NPB_PAD * sizeof(unsigned));
    size_t o_ofs2 = carve((size_t)NJB * NPB_PAD * sizeof(unsigned));

    const bool ok = (NP == 4 * N) && (NP % 4 == 0) &&
                    (NPB <= NPB_PAD) && (NJB <= MAX_NJB) && (off <= ws_size);
    if (!ok) {
        hipLaunchKernelGGL(zero_out_kernel, dim3(1), dim3(1), 0, stream, out);
        const int block = 256, grid = (N + block - 1) / block;
        hipLaunchKernelGGL(wasll_fallback, dim3(grid), dim3(block), 0, stream,
                           (const float2*)posf, (const int4*)fnp, net_weights,
                           inv_gamma, slrx, slry, out, N);
        return;
    }

    char* ws = (char*)d_ws;
    unsigned short* pinoff16 = (unsigned short*)(ws + o_po);
    unsigned*       jarr     = (unsigned*)(ws + o_jarr);
    unsigned*       ent2     = (unsigned*)(ws + o_ent2);
    unsigned*       cnt      = (unsigned*)(ws + o_cnt);
    unsigned*       ofs1     = (unsigned*)(ws + o_ofs1);
    unsigned*       ofs2     = (unsigned*)(ws + o_ofs2);

    hipLaunchKernelGGL(p1a_count, dim3(NCH), dim3(512), 0, stream,
                       (const int4*)fnp, NP, cnt);
    hipLaunchKernelGGL(p1b_scan, dim3(4 + NJB), dim3(256), 0, stream,
                       cnt, NCH, NJB, ofs1, ofs2, out);
    hipLaunchKernelGGL(p1c_scatter, dim3(8 * Qc), dim3(512), 0, stream,
                       (const int4*)fnp, ofs1, NP, NCH, Qc, pinoff16, jarr);

    // d = 0 (x): early-exits when num_slrX <= 1
    hipLaunchKernelGGL(p2_gather, dim3(8 * Qp), dim3(512), 0, stream,
                       pinoff16, jarr, (const float2*)posf, ofs2,
                       slrx, slry, 0, NP, NPB, NJB, Qp, ent2);
    hipLaunchKernelGGL(p3_compute, dim3(NJB), dim3(512), 0, stream,
                       ent2, net_weights, inv_gamma, slrx, slry, 0, NP, out);
    // d = 1 (y)
    hipLaunchKernelGGL(p2_gather, dim3(8 * Qp), dim3(512), 0, stream,
                       pinoff16, jarr, (const float2*)posf, ofs2,
                       slrx, slry, 1, NP, NPB, NJB, Qp, ent2);
    hipLaunchKernelGGL(p3_compute, dim3(NJB), dim3(512), 0, stream,
                       ent2, net_weights, inv_gamma, slrx, slry, 1, NP, out);
}